// Round 15
// baseline (393.125 us; speedup 1.0000x reference)
//
#include <hip/hip_runtime.h>
#include <math.h>

// Output = Re(H) as float32, shape (B,8,8) row-major, 64 floats = 16 float4/record.
// Quads: q1=(1,0,0,0) q3=(0,1,0,0) q5=(0,0,1,0) q7=(0,0,0,1)
//        q8=(1.5,0,m00r,offr) q10=(0,1.5,offr,m11r)
//        q12=(m00r,offr,1.5,0) q14=(offr,m11r,0,1.5); all others zero.
//   c1 = cos(sqrt3*kx), c2 = cos(sqrt3/2*kx + 1.5*ky)
//   m00r = -(0.75+0.75*c1)  offr = -sqrt3/4*(1-c1)  m11r = -(0.25+0.25*c1+c2)
//
// R13 post-mortem: __cosf == libm cosf == NT == multi-store (all ~70-76 us vs
// 40 us floor). DIAGNOSTIC ROUND: wreps extra dependency-free streaming stores
// of v into distinct 256MB d_ws regions (scratch; semantics unchanged) to
// (1) surface our dispatch in rocprof top-5 and (2) measure the pure store
// path via the marginal cost per extra 256MB pass.

typedef float vf4 __attribute__((ext_vector_type(4)));

#define SQRT3F 1.73205080756887729f
#define S34F   0.43301270189221933f   // sqrt(3)/4

__global__ void __launch_bounds__(256)
bulk_hamiltonian_diag_kernel(const float* __restrict__ k, vf4* __restrict__ out,
                             vf4* __restrict__ ws, int wreps, int n4) {
    const int i = blockIdx.x * blockDim.x + threadIdx.x;
    if (i >= n4) return;
    const int b = i >> 4;   // record index
    const int q = i & 15;   // float4 index within record
    vf4 v = (vf4)(0.0f);
    if ((q & 9) == 8) {     // q in {8,10,12,14}: the k-dependent quads
        const float kx = k[2 * (size_t)b];
        const float ky = k[2 * (size_t)b + 1];
        const float c1 = __cosf(kx * SQRT3F);                      // v_cos_f32
        const float c2 = __cosf(fmaf(ky, 1.5f, kx * (0.5f * SQRT3F)));
        const float m00r = fmaf(-0.75f, c1, -0.75f);
        const float offr = fmaf(S34F, c1, -S34F);
        const float m11r = -fmaf(0.25f, c1, 0.25f + c2);
        if (q == 8)       { v.x = 1.5f; v.z = m00r; v.w = offr; }
        else if (q == 10) { v.y = 1.5f; v.z = offr; v.w = m11r; }
        else if (q == 12) { v.x = m00r; v.y = offr; v.z = 1.5f; }
        else              { v.x = offr; v.y = m11r; v.w = 1.5f; }
    } else {
        // identity block: q=1,3,5,7 -> unit in slot q>>1; everything else zero
        const float one = (q < 8 && (q & 1)) ? 1.0f : 0.0f;
        const int h = q >> 1;
        v.x = (h == 0) ? one : 0.0f;
        v.y = (h == 1) ? one : 0.0f;
        v.z = (h == 2) ? one : 0.0f;
        v.w = (h == 3) ? one : 0.0f;
    }
    // dependency-free extra streaming passes into scratch (diagnostic only)
    for (int r = 0; r < wreps; ++r)
        ws[(size_t)r * (size_t)n4 + (size_t)i] = v;
    out[i] = v;   // the real output store, identical to R13
}

extern "C" void kernel_launch(void* const* d_in, const int* in_sizes, int n_in,
                              void* d_out, int out_size, void* d_ws, size_t ws_size,
                              hipStream_t stream) {
    const float* k = (const float*)d_in[0];
    const long long B = in_sizes[0] / 2;     // k is (B,2,1) float32
    long long n4_ll = B * 16;                // 64 floats = 16 float4 per record
    const long long n4_guar = (long long)out_size / 4;   // guaranteed floats/4
    if (n4_guar > 0 && n4_guar < n4_ll) n4_ll = n4_guar;
    if (n4_ll <= 0) return;
    const int n4 = (int)n4_ll;
    // how many full 256MB (n4*16B) diagnostic regions fit in d_ws (cap 3)
    long long wreps_ll = (long long)(ws_size / ((size_t)n4 * 16));
    if (wreps_ll > 3) wreps_ll = 3;
    if (wreps_ll < 0) wreps_ll = 0;
    const int wreps = (int)wreps_ll;
    const int block = 256;
    const int grid = (int)((n4_ll + block - 1) / block);
    bulk_hamiltonian_diag_kernel<<<grid, block, 0, stream>>>(
        k, (vf4*)d_out, (vf4*)d_ws, wreps, n4);
}